// Round 8
// baseline (57.013 us; speedup 1.0000x reference)
//
#include <hip/hip_runtime.h>

// RBF: out[n,m] = exp(-0.5 * max(||A_n||^2 + ||B_m||^2 - 2 A_n.B_m, 0))
// N=M=8192, D=64, fp32 in/out.
// fp16 32x32x16 MFMA cross-term, exact fp32 norms, exp2 epilogue, nt stores.
// Round 8 = round 6 resubmit x2 (container unresponsive twice): 64x256 tile
// (1 KB contiguous rows per block) + store loop walks columns-within-row
// first -> DRAM page locality for the write stream.
// 256 threads / 4 waves (2 row x 2 col, each 32x128), XOR-swizzled LDS.

constexpr int Mdim = 8192;
constexpr int D    = 64;
constexpr int BM   = 64;
constexpr int BN   = 256;
constexpr float NEG_HALF_L2E = -0.72134752044448170f; // -0.5*log2(e)
constexpr float L2E          =  1.44269504088896340f; //  log2(e)

typedef __attribute__((ext_vector_type(8)))  _Float16 f16x8;
typedef __attribute__((ext_vector_type(16))) float    f32x16;

__global__ __launch_bounds__(256, 3) void rbf_mfma_58720792871618(
    const float* __restrict__ A, const float* __restrict__ B, float* __restrict__ C)
{
    __shared__ _Float16 Ash[BM * D];   // 64 rows x 128 B, XOR-swizzled 16B slots
    __shared__ _Float16 Bsh[BN * D];   // 256 rows x 128 B
    __shared__ float pA[BM];           // -0.5*log2e * ||row||^2
    __shared__ float pB[BN];

    const int tid  = threadIdx.x;
    const int lane = tid & 63;
    const int wid  = tid >> 6;
    const int row0 = blockIdx.y * BM;
    const int col0 = blockIdx.x * BN;

    // ---------------- stage: fp32 -> fp16 into swizzled LDS + fp32 norms ----------------
    {
        // B: thread t stages full B-row t (64 floats), norm in-thread.
        const int rb = tid;
        const float4* gb = reinterpret_cast<const float4*>(B + (size_t)(col0 + rb) * D);
        float sb = 0.f;
        f16x8 hb[8];
        #pragma unroll
        for (int k = 0; k < 16; ++k) {
            const float4 v = gb[k];
            sb = fmaf(v.x, v.x, fmaf(v.y, v.y, fmaf(v.z, v.z, fmaf(v.w, v.w, sb))));
            const int t = k >> 1, o = (k & 1) * 4;
            hb[t][o + 0] = (_Float16)v.x; hb[t][o + 1] = (_Float16)v.y;
            hb[t][o + 2] = (_Float16)v.z; hb[t][o + 3] = (_Float16)v.w;
        }
        char* bbase = reinterpret_cast<char*>(Bsh) + rb * 128;
        #pragma unroll
        for (int t = 0; t < 8; ++t) {
            const int sw = (t * 16) ^ ((rb & 7) << 4);
            *reinterpret_cast<f16x8*>(bbase + sw) = hb[t];
        }
        pB[rb] = NEG_HALF_L2E * sb;

        // A: 4 threads per row; thread stages 16 floats (quarter row).
        const int ra = tid >> 2;
        const int c0 = (tid & 3) * 16;
        const float4* ga = reinterpret_cast<const float4*>(A + (size_t)(row0 + ra) * D + c0);
        float sa = 0.f;
        f16x8 ha[2];
        #pragma unroll
        for (int k = 0; k < 4; ++k) {
            const float4 v = ga[k];
            sa = fmaf(v.x, v.x, fmaf(v.y, v.y, fmaf(v.z, v.z, fmaf(v.w, v.w, sa))));
            const int t = k >> 1, o = (k & 1) * 4;
            ha[t][o + 0] = (_Float16)v.x; ha[t][o + 1] = (_Float16)v.y;
            ha[t][o + 2] = (_Float16)v.z; ha[t][o + 3] = (_Float16)v.w;
        }
        char* abase = reinterpret_cast<char*>(Ash) + ra * 128;
        #pragma unroll
        for (int t = 0; t < 2; ++t) {
            const int sw = (c0 * 2 + t * 16) ^ ((ra & 7) << 4);
            *reinterpret_cast<f16x8*>(abase + sw) = ha[t];
        }
        sa += __shfl_xor(sa, 1);
        sa += __shfl_xor(sa, 2);
        if ((tid & 3) == 0) pA[ra] = NEG_HALF_L2E * sa;
    }
    __syncthreads();

    // ---------------- MFMA: 32x128 per wave, 1x4 fragments of 32x32, K=64 ----------------
    // C/D: col = lane&31, row = (reg&3) + 8*(reg>>2) + 4*(lane>>5)
    const int wr  = (wid >> 1) * 32;   // wave row base in tile
    const int wc  = (wid & 1) * 128;   // wave col base in tile
    const int l31 = lane & 31;
    const int hi  = lane >> 5;

    const int arow = wr + l31;
    const char* ab = reinterpret_cast<const char*>(Ash);
    const char* bb = reinterpret_cast<const char*>(Bsh);

    f32x16 acc[4] = {};

    #pragma unroll
    for (int ks = 0; ks < 4; ++ks) {
        const int kb = ks * 32 + hi * 16;   // byte offset of this lane's k-slice
        const f16x8 af = *reinterpret_cast<const f16x8*>(
            ab + arow * 128 + (kb ^ ((arow & 7) << 4)));
        #pragma unroll
        for (int nf = 0; nf < 4; ++nf) {
            const int brow = wc + nf * 32 + l31;
            const f16x8 bf = *reinterpret_cast<const f16x8*>(
                bb + brow * 128 + (kb ^ ((brow & 7) << 4)));
            acc[nf] = __builtin_amdgcn_mfma_f32_32x32x16_f16(af, bf, acc[nf], 0, 0, 0);
        }
    }

    // ---------------- epilogue: row-major store order for page locality ----------------
    // Per (g,q): one row-pair; inner nf walks 4 col segments (512 B temporal run).
    float pb[4];
    #pragma unroll
    for (int nf = 0; nf < 4; ++nf) pb[nf] = pB[wc + nf * 32 + l31];

    #pragma unroll
    for (int g = 0; g < 4; ++g) {
        #pragma unroll
        for (int q = 0; q < 4; ++q) {
            const int rt = wr + 4 * hi + 8 * g + q;   // row in tile
            const float pav = pA[rt];
            float* crow = C + (size_t)(row0 + rt) * Mdim + (col0 + wc + l31);
            const int e = g * 4 + q;
            #pragma unroll
            for (int nf = 0; nf < 4; ++nf) {
                const float t = fmaf(L2E, acc[nf][e], pav + pb[nf]);
                __builtin_nontemporal_store(
                    __builtin_amdgcn_exp2f(fminf(t, 0.0f)), crow + nf * 32);
            }
        }
    }
}

extern "C" void kernel_launch(void* const* d_in, const int* /*in_sizes*/, int /*n_in*/,
                              void* d_out, int /*out_size*/, void* /*d_ws*/, size_t /*ws_size*/,
                              hipStream_t stream)
{
    const float* A = (const float*)d_in[0];   // input_1 [8192, 64]
    const float* B = (const float*)d_in[1];   // input_2 [8192, 64]
    float* C = (float*)d_out;                 // [8192, 8192]
    dim3 grid(Mdim / BN, 8192 / BM);
    rbf_mfma_58720792871618<<<grid, 256, 0, stream>>>(A, B, C);
}

// Round 9
// 55.652 us; speedup vs baseline: 1.0245x; 1.0245x over previous
//
#include <hip/hip_runtime.h>

// RBF: out[n,m] = exp(-0.5 * max(||A_n||^2 + ||B_m||^2 - 2 A_n.B_m, 0))
// N=M=8192, D=64, fp32 in/out.
// fp16 32x32x16 MFMA cross-term, exact fp32 norms, exp2 epilogue, nt stores.
// Round 9 change vs R5 (best, 53.6us): bijective XCD-aware block swizzle --
// XCD j owns a contiguous 8-block-row band of C (32 MB), so each XCD's write
// stream sweeps sequentially and its A-band/B panels stay L2-resident.
// 128x128 tile / 256 threads (4 waves, 2x2 of 64x64), XOR-swizzled LDS.

constexpr int Mdim = 8192;
constexpr int D    = 64;
constexpr int BM   = 128;
constexpr int BN   = 128;
constexpr int NXCD = 8;
constexpr float NEG_HALF_L2E = -0.72134752044448170f; // -0.5*log2(e)
constexpr float L2E          =  1.44269504088896340f; //  log2(e)

typedef __attribute__((ext_vector_type(8)))  _Float16 f16x8;
typedef __attribute__((ext_vector_type(16))) float    f32x16;

__global__ __launch_bounds__(256, 3) void rbf_mfma_58720792871618(
    const float* __restrict__ A, const float* __restrict__ B, float* __restrict__ C)
{
    __shared__ _Float16 Ash[BM * D];   // row-major, 128 B/row, XOR-swizzled 16B slots
    __shared__ _Float16 Bsh[BN * D];
    __shared__ float pA[BM];           // -0.5*log2e * ||row||^2
    __shared__ float pB[BN];

    const int tid  = threadIdx.x;
    const int lane = tid & 63;
    const int wid  = tid >> 6;

    // ---- bijective XCD swizzle: dispatch id -> tile id ----
    // XCD = lin % 8 (HW round-robin). Give XCD j tiles [j*512, (j+1)*512):
    // 8 contiguous block-rows = a contiguous 32 MB band of C.
    const int lin   = blockIdx.x;                    // 0..4095
    const int tileid = (lin & (NXCD - 1)) * (4096 / NXCD) + (lin >> 3);
    const int row0  = (tileid >> 6) * BM;            // 64 tiles per block-row
    const int col0  = (tileid & 63) * BN;

    // ---------------- stage: fp32 -> fp16 into swizzled LDS + fp32 norms ----------------
    {
        const int r  = tid >> 1;           // tile row 0..127 (A and B)
        const int c0 = (tid & 1) * 32;     // column half
        const float4* ga = reinterpret_cast<const float4*>(A + (size_t)(row0 + r) * D + c0);
        const float4* gb = reinterpret_cast<const float4*>(B + (size_t)(col0 + r) * D + c0);

        float sa = 0.f, sb = 0.f;
        f16x8 ha[4], hb[4];
        #pragma unroll
        for (int k = 0; k < 8; ++k) {
            const float4 v = ga[k];
            sa = fmaf(v.x, v.x, fmaf(v.y, v.y, fmaf(v.z, v.z, fmaf(v.w, v.w, sa))));
            const int t = k >> 1, o = (k & 1) * 4;
            ha[t][o + 0] = (_Float16)v.x; ha[t][o + 1] = (_Float16)v.y;
            ha[t][o + 2] = (_Float16)v.z; ha[t][o + 3] = (_Float16)v.w;
        }
        #pragma unroll
        for (int k = 0; k < 8; ++k) {
            const float4 v = gb[k];
            sb = fmaf(v.x, v.x, fmaf(v.y, v.y, fmaf(v.z, v.z, fmaf(v.w, v.w, sb))));
            const int t = k >> 1, o = (k & 1) * 4;
            hb[t][o + 0] = (_Float16)v.x; hb[t][o + 1] = (_Float16)v.y;
            hb[t][o + 2] = (_Float16)v.z; hb[t][o + 3] = (_Float16)v.w;
        }

        char* abase = reinterpret_cast<char*>(Ash) + r * 128;
        char* bbase = reinterpret_cast<char*>(Bsh) + r * 128;
        #pragma unroll
        for (int t = 0; t < 4; ++t) {
            const int sw = (c0 * 2 + t * 16) ^ ((r & 7) << 4);
            *reinterpret_cast<f16x8*>(abase + sw) = ha[t];
        }
        #pragma unroll
        for (int t = 0; t < 4; ++t) {
            const int sw = (c0 * 2 + t * 16) ^ ((r & 7) << 4);
            *reinterpret_cast<f16x8*>(bbase + sw) = hb[t];
        }

        sa += __shfl_xor(sa, 1);
        sb += __shfl_xor(sb, 1);
        if ((tid & 1) == 0) { pA[r] = NEG_HALF_L2E * sa; pB[r] = NEG_HALF_L2E * sb; }
    }
    __syncthreads();

    // ---------------- MFMA: 64x64 per wave, 2x2 fragments of 32x32, K=64 ----------------
    // C/D: col = lane&31, row = (reg&3) + 8*(reg>>2) + 4*(lane>>5)
    const int wr  = (wid >> 1) * 64;   // wave row base in tile
    const int wc  = (wid & 1) * 64;    // wave col base in tile
    const int l31 = lane & 31;
    const int hi  = lane >> 5;

    const int arow0 = wr + l31,  arow1 = wr + 32 + l31;
    const int brow0 = wc + l31,  brow1 = wc + 32 + l31;
    const char* ab = reinterpret_cast<const char*>(Ash);
    const char* bb = reinterpret_cast<const char*>(Bsh);

    f32x16 acc[2][2] = {};

    #pragma unroll
    for (int ks = 0; ks < 4; ++ks) {
        const int kb = ks * 32 + hi * 16;   // byte offset of this lane's k-slice
        f16x8 af[2], bf[2];
        af[0] = *reinterpret_cast<const f16x8*>(ab + arow0 * 128 + (kb ^ ((arow0 & 7) << 4)));
        af[1] = *reinterpret_cast<const f16x8*>(ab + arow1 * 128 + (kb ^ ((arow1 & 7) << 4)));
        bf[0] = *reinterpret_cast<const f16x8*>(bb + brow0 * 128 + (kb ^ ((brow0 & 7) << 4)));
        bf[1] = *reinterpret_cast<const f16x8*>(bb + brow1 * 128 + (kb ^ ((brow1 & 7) << 4)));
        #pragma unroll
        for (int mf = 0; mf < 2; ++mf)
            #pragma unroll
            for (int nf = 0; nf < 2; ++nf)
                acc[mf][nf] = __builtin_amdgcn_mfma_f32_32x32x16_f16(
                    af[mf], bf[nf], acc[mf][nf], 0, 0, 0);
    }

    // ---------------- epilogue: t = log2e*acc + pa + pb; out = exp2(min(t,0)) ----------------
    // Nontemporal scalar-dword stores: 2 rows x 128 B contiguous per instruction.
    const float pb0 = pB[wc + l31];
    const float pb1 = pB[wc + 32 + l31];

    #pragma unroll
    for (int mf = 0; mf < 2; ++mf) {
        #pragma unroll
        for (int g = 0; g < 4; ++g) {
            #pragma unroll
            for (int q = 0; q < 4; ++q) {
                const int rt = wr + mf * 32 + 4 * hi + 8 * g + q;   // row in tile
                const float pav = pA[rt];
                float* crow = C + (size_t)(row0 + rt) * Mdim + (col0 + wc + l31);
                const int e = g * 4 + q;
                float t0 = fmaf(L2E, acc[mf][0][e], pav + pb0);
                float t1 = fmaf(L2E, acc[mf][1][e], pav + pb1);
                __builtin_nontemporal_store(
                    __builtin_amdgcn_exp2f(fminf(t0, 0.0f)), crow + 0);
                __builtin_nontemporal_store(
                    __builtin_amdgcn_exp2f(fminf(t1, 0.0f)), crow + 32);
            }
        }
    }
}

extern "C" void kernel_launch(void* const* d_in, const int* /*in_sizes*/, int /*n_in*/,
                              void* d_out, int /*out_size*/, void* /*d_ws*/, size_t /*ws_size*/,
                              hipStream_t stream)
{
    const float* A = (const float*)d_in[0];   // input_1 [8192, 64]
    const float* B = (const float*)d_in[1];   // input_2 [8192, 64]
    float* C = (float*)d_out;                 // [8192, 8192]
    rbf_mfma_58720792871618<<<dim3(4096), 256, 0, stream>>>(A, B, C);
}

// Round 10
// 55.220 us; speedup vs baseline: 1.0325x; 1.0078x over previous
//
#include <hip/hip_runtime.h>

// RBF: out[n,m] = exp(-0.5 * max(||A_n||^2 + ||B_m||^2 - 2 A_n.B_m, 0))
// N=M=8192, D=64, fp32 in/out.
// fp16 32x32x16 MFMA cross-term, exact fp32 norms, exp2 epilogue, nt stores.
// Round 10 change vs R5 (best, 53.6us): __launch_bounds__(256,4) -> 4 blocks/CU
// (LDS 33.5KB x4 = 134KB fits) for deeper store-queue / better phase mixing.
// 128x128 tile / 256 threads (4 waves, 2x2 of 64x64), XOR-swizzled LDS.

constexpr int Mdim = 8192;
constexpr int D    = 64;
constexpr int BM   = 128;
constexpr int BN   = 128;
constexpr float NEG_HALF_L2E = -0.72134752044448170f; // -0.5*log2(e)
constexpr float L2E          =  1.44269504088896340f; //  log2(e)

typedef __attribute__((ext_vector_type(8)))  _Float16 f16x8;
typedef __attribute__((ext_vector_type(16))) float    f32x16;

__global__ __launch_bounds__(256, 4) void rbf_mfma_58720792871618(
    const float* __restrict__ A, const float* __restrict__ B, float* __restrict__ C)
{
    __shared__ _Float16 Ash[BM * D];   // row-major, 128 B/row, XOR-swizzled 16B slots
    __shared__ _Float16 Bsh[BN * D];
    __shared__ float pA[BM];           // -0.5*log2e * ||row||^2
    __shared__ float pB[BN];

    const int tid  = threadIdx.x;
    const int lane = tid & 63;
    const int wid  = tid >> 6;
    const int row0 = blockIdx.y * BM;
    const int col0 = blockIdx.x * BN;

    // ---------------- stage: fp32 -> fp16 into swizzled LDS + fp32 norms ----------------
    {
        const int r  = tid >> 1;           // tile row 0..127 (A and B)
        const int c0 = (tid & 1) * 32;     // column half
        const float4* ga = reinterpret_cast<const float4*>(A + (size_t)(row0 + r) * D + c0);
        const float4* gb = reinterpret_cast<const float4*>(B + (size_t)(col0 + r) * D + c0);

        float sa = 0.f, sb = 0.f;
        f16x8 ha[4], hb[4];
        #pragma unroll
        for (int k = 0; k < 8; ++k) {
            const float4 v = ga[k];
            sa = fmaf(v.x, v.x, fmaf(v.y, v.y, fmaf(v.z, v.z, fmaf(v.w, v.w, sa))));
            const int t = k >> 1, o = (k & 1) * 4;
            ha[t][o + 0] = (_Float16)v.x; ha[t][o + 1] = (_Float16)v.y;
            ha[t][o + 2] = (_Float16)v.z; ha[t][o + 3] = (_Float16)v.w;
        }
        #pragma unroll
        for (int k = 0; k < 8; ++k) {
            const float4 v = gb[k];
            sb = fmaf(v.x, v.x, fmaf(v.y, v.y, fmaf(v.z, v.z, fmaf(v.w, v.w, sb))));
            const int t = k >> 1, o = (k & 1) * 4;
            hb[t][o + 0] = (_Float16)v.x; hb[t][o + 1] = (_Float16)v.y;
            hb[t][o + 2] = (_Float16)v.z; hb[t][o + 3] = (_Float16)v.w;
        }

        char* abase = reinterpret_cast<char*>(Ash) + r * 128;
        char* bbase = reinterpret_cast<char*>(Bsh) + r * 128;
        #pragma unroll
        for (int t = 0; t < 4; ++t) {
            const int sw = (c0 * 2 + t * 16) ^ ((r & 7) << 4);
            *reinterpret_cast<f16x8*>(abase + sw) = ha[t];
        }
        #pragma unroll
        for (int t = 0; t < 4; ++t) {
            const int sw = (c0 * 2 + t * 16) ^ ((r & 7) << 4);
            *reinterpret_cast<f16x8*>(bbase + sw) = hb[t];
        }

        sa += __shfl_xor(sa, 1);
        sb += __shfl_xor(sb, 1);
        if ((tid & 1) == 0) { pA[r] = NEG_HALF_L2E * sa; pB[r] = NEG_HALF_L2E * sb; }
    }
    __syncthreads();

    // ---------------- MFMA: 64x64 per wave, 2x2 fragments of 32x32, K=64 ----------------
    // C/D: col = lane&31, row = (reg&3) + 8*(reg>>2) + 4*(lane>>5)
    const int wr  = (wid >> 1) * 64;   // wave row base in tile
    const int wc  = (wid & 1) * 64;    // wave col base in tile
    const int l31 = lane & 31;
    const int hi  = lane >> 5;

    const int arow0 = wr + l31,  arow1 = wr + 32 + l31;
    const int brow0 = wc + l31,  brow1 = wc + 32 + l31;
    const char* ab = reinterpret_cast<const char*>(Ash);
    const char* bb = reinterpret_cast<const char*>(Bsh);

    f32x16 acc[2][2] = {};

    #pragma unroll
    for (int ks = 0; ks < 4; ++ks) {
        const int kb = ks * 32 + hi * 16;   // byte offset of this lane's k-slice
        f16x8 af[2], bf[2];
        af[0] = *reinterpret_cast<const f16x8*>(ab + arow0 * 128 + (kb ^ ((arow0 & 7) << 4)));
        af[1] = *reinterpret_cast<const f16x8*>(ab + arow1 * 128 + (kb ^ ((arow1 & 7) << 4)));
        bf[0] = *reinterpret_cast<const f16x8*>(bb + brow0 * 128 + (kb ^ ((brow0 & 7) << 4)));
        bf[1] = *reinterpret_cast<const f16x8*>(bb + brow1 * 128 + (kb ^ ((brow1 & 7) << 4)));
        #pragma unroll
        for (int mf = 0; mf < 2; ++mf)
            #pragma unroll
            for (int nf = 0; nf < 2; ++nf)
                acc[mf][nf] = __builtin_amdgcn_mfma_f32_32x32x16_f16(
                    af[mf], bf[nf], acc[mf][nf], 0, 0, 0);
    }

    // ---------------- epilogue: t = log2e*acc + pa + pb; out = exp2(min(t,0)) ----------------
    // Nontemporal scalar-dword stores: 2 rows x 128 B contiguous per instruction.
    const float pb0 = pB[wc + l31];
    const float pb1 = pB[wc + 32 + l31];

    #pragma unroll
    for (int mf = 0; mf < 2; ++mf) {
        #pragma unroll
        for (int g = 0; g < 4; ++g) {
            #pragma unroll
            for (int q = 0; q < 4; ++q) {
                const int rt = wr + mf * 32 + 4 * hi + 8 * g + q;   // row in tile
                const float pav = pA[rt];
                float* crow = C + (size_t)(row0 + rt) * Mdim + (col0 + wc + l31);
                const int e = g * 4 + q;
                float t0 = fmaf(L2E, acc[mf][0][e], pav + pb0);
                float t1 = fmaf(L2E, acc[mf][1][e], pav + pb1);
                __builtin_nontemporal_store(
                    __builtin_amdgcn_exp2f(fminf(t0, 0.0f)), crow + 0);
                __builtin_nontemporal_store(
                    __builtin_amdgcn_exp2f(fminf(t1, 0.0f)), crow + 32);
            }
        }
    }
}

extern "C" void kernel_launch(void* const* d_in, const int* /*in_sizes*/, int /*n_in*/,
                              void* d_out, int /*out_size*/, void* /*d_ws*/, size_t /*ws_size*/,
                              hipStream_t stream)
{
    const float* A = (const float*)d_in[0];   // input_1 [8192, 64]
    const float* B = (const float*)d_in[1];   // input_2 [8192, 64]
    float* C = (float*)d_out;                 // [8192, 8192]
    dim3 grid(Mdim / BN, 8192 / BM);
    rbf_mfma_58720792871618<<<grid, 256, 0, stream>>>(A, B, C);
}